// Round 1
// baseline (1172.527 us; speedup 1.0000x reference)
//
#include <hip/hip_runtime.h>

// Problem constants (fixed by the reference setup)
#define B_ 64
#define T_ 1024
#define I_ 64
#define H_ 512
#define R_ 8
#define O_ 64

// fast tanh: tanh(x) = 1 - 2/(exp2(2*log2(e)*x)+1); well-behaved at +-inf
__device__ __forceinline__ float ftanh(float x) {
    float e = __builtin_amdgcn_exp2f(x * 2.8853900817779268f); // 2*log2(e)
    return 1.0f - 2.0f * __builtin_amdgcn_rcpf(e + 1.0f);
}

__device__ __forceinline__ float4 f4add(float4 a, float4 b) {
    return make_float4(a.x + b.x, a.y + b.y, a.z + b.z, a.w + b.w);
}

// DPP lane-permute move (VALU pipe, ~4cy; no LDS traffic)
template <int CTRL>
__device__ __forceinline__ float dppmov(float x) {
    return __int_as_float(__builtin_amdgcn_update_dpp(
        0, __float_as_int(x), CTRL, 0xF, 0xF, true));
}

// ---------------------------------------------------------------------------
// Kernel 1: drive[b,t,h] = 0.2*(sum_i u[b,t,i]*W_in[h,i] + b_in[h])
//                        + 0.05*noise[t,b,h]
// written into the traj region of d_out (scan consumes slot t then overwrites)
// grid: (T/64, H/128, B), block 256. LDS-tiled fp32.
// ---------------------------------------------------------------------------
__global__ __launch_bounds__(256) void inp_gemm(
    const float* __restrict__ u, const float* __restrict__ W_in,
    const float* __restrict__ b_in, const float* __restrict__ noise,
    float* __restrict__ drive)
{
    __shared__ float4 su4[64 * 17];   // u tile [64 t][16 f4], row pad 17
    __shared__ float4 sw4[128 * 17];  // W tile [128 h][16 f4], row pad 17

    const int tid = threadIdx.x;
    const int t0 = blockIdx.x * 64;
    const int h0 = blockIdx.y * 128;
    const int b  = blockIdx.z;

    const float4* usrc = (const float4*)(u + (size_t)(b * T_ + t0) * I_);
    const float4* wsrc = (const float4*)(W_in + (size_t)h0 * I_);

    #pragma unroll
    for (int k = tid; k < 64 * 16; k += 256)
        su4[(k >> 4) * 17 + (k & 15)] = usrc[k];
    #pragma unroll
    for (int k = tid; k < 128 * 16; k += 256)
        sw4[(k >> 4) * 17 + (k & 15)] = wsrc[k];
    __syncthreads();

    const int tg = tid >> 4;   // 16 groups -> 4 t each
    const int hi = tid & 15;   // h = h0 + hi + 16*c

    float acc[4][8];
    #pragma unroll
    for (int a = 0; a < 4; ++a)
        #pragma unroll
        for (int c = 0; c < 8; ++c) acc[a][c] = 0.0f;

    #pragma unroll
    for (int i4 = 0; i4 < 16; ++i4) {
        float4 uv[4], wv[8];
        #pragma unroll
        for (int a = 0; a < 4; ++a) uv[a] = su4[(tg * 4 + a) * 17 + i4];
        #pragma unroll
        for (int c = 0; c < 8; ++c) wv[c] = sw4[(hi + 16 * c) * 17 + i4];
        #pragma unroll
        for (int a = 0; a < 4; ++a)
            #pragma unroll
            for (int c = 0; c < 8; ++c)
                acc[a][c] += uv[a].x * wv[c].x + uv[a].y * wv[c].y +
                             uv[a].z * wv[c].z + uv[a].w * wv[c].w;
    }

    #pragma unroll
    for (int c = 0; c < 8; ++c) {
        const int h = h0 + hi + 16 * c;
        float bi = b_in[h];
        #pragma unroll
        for (int a = 0; a < 4; ++a) {
            const int t = t0 + tg * 4 + a;
            float nz = noise[((size_t)t * B_ + b) * H_ + h];
            drive[(size_t)(b * T_ + t) * H_ + h] =
                0.2f * (acc[a][c] + bi) + 0.05f * nz;
        }
    }
}

// ---------------------------------------------------------------------------
// Kernel 2: sequential scan. One block per batch (64 blocks x 256 threads),
// thread owns h = 2*tid, 2*tid+1.
//
// Per step: x_new = 0.8*x + drive[t] + rec_scaled(x_{t-2})
//   - rec lagged 2 steps (term magnitude ~4e-8 vs x ~0.2 -> deviation ~1e-8)
//     so the x->x critical path is 2 FMAs; the 16-way projection reduction is
//     software-pipelined across ONE raw s_barrier per step.
//   - fold-butterfly done with DPP basis {xor1(quad_perm), xor2(quad_perm),
//     xor7(row_half_mirror), xor8(row_ror:8)}; weight slots pre-permuted by
//     the matching linear map g(l) so each stage is p[k] += dpp(p[k+NV]).
//   - raw asm barrier with lgkmcnt(0)-only wait: global prefetch loads and
//     traj stores stay in flight across barriers (no vmcnt(0) drain).
//   - cross-wave combine: wave w writes its 16 sums to a mod-4-rotated LDS
//     slot; every lane combines 4x16 floats via broadcast ds_read_b128.
// ---------------------------------------------------------------------------
__global__ __launch_bounds__(256) void scan_kernel(
    const float* __restrict__ x0,
    const float* __restrict__ Lm, const float* __restrict__ Mm,
    const float* __restrict__ Nm,
    float* __restrict__ traj, float* __restrict__ xlast)
{
    const int tid  = threadIdx.x;
    const int b    = blockIdx.x;
    const int h0   = tid * 2;
    const int lane = tid & 63;
    const int wv   = tid >> 6;
    const int lm   = lane & 15;
    // linear map g: g(1)=8, g(2)=4, g(4)=14, g(8)=1  (basis match for the
    // DPP stage masks 1,2,7,8 folding value-bits 8,4,2,1)
    const int gl = ((lm & 1) ? 8 : 0) ^ ((lm & 2) ? 4 : 0) ^
                   ((lm & 4) ? 14 : 0) ^ ((lm & 8) ? 1 : 0);

    // permuted projection weights: slot k holds value v = k ^ gl
    // (v<8 -> column v of M ; v>=8 -> column v-8 of N)
    float w0[16], w1[16];
    #pragma unroll
    for (int k = 0; k < 16; ++k) {
        const int v = k ^ gl;
        const float* src = (v < 8) ? Mm : Nm;
        const int col = v & 7;
        w0[k] = src[h0 * R_ + col];
        w1[k] = src[(h0 + 1) * R_ + col];
    }
    // L columns pre-scaled by tau*scale = 0.2/(H*H)
    float l0[8], l1[8];
    const float cs = 0.2f / (512.0f * 512.0f);
    #pragma unroll
    for (int j = 0; j < 8; ++j) {
        l0[j] = Lm[h0 * R_ + j] * cs;
        l1[j] = Lm[(h0 + 1) * R_ + j] * cs;
    }

    float2 xv = *(const float2*)(x0 + (size_t)b * H_ + h0);

    float2* tptr = (float2*)traj + (size_t)b * (T_ * (H_ / 2)) + tid;

    // 4 rotating reduction slots: written at t%4, read at (t+2)%4 two steps
    // later, rewritten at t+4. One barrier per step separates all phases.
    __shared__ __align__(16) float red4[4][64];
    ((float*)red4)[tid] = 0.0f;   // slots read at t=0,1 must be zero (rec=0)
    __syncthreads();

    // drive prefetch, distance 3, 4 rotating register slots
    float2 db[4];
    db[0] = tptr[0];
    db[1] = tptr[256];
    db[2] = tptr[512];
    const float2* pf = tptr + 3 * 256;
    float2*       st = tptr;
    float2 xstA, xstB;  // 2-deep store-source rotation (avoid WAR vm-waits)

    auto step = [&](int t, int SA, float2& xst) {
        const int SR = (SA + 2) & 3;   // combine slot (written at t-2)
        const int SP = (SA + 3) & 3;   // prefetch slot (consumed at t+3)

        if (t + 3 < T_) db[SP] = *pf;
        pf += 256;

        // ---- launch reduction of entering x_t (consumed at step t+2) ----
        const float r0 = ftanh(xv.x), r1 = ftanh(xv.y);
        float p[16];
        #pragma unroll
        for (int k = 0; k < 16; ++k) p[k] = r0 * w0[k] + r1 * w1[k];
        #pragma unroll
        for (int k = 0; k < 8; ++k) p[k] += dppmov<0xB1>(p[k + 8]);  // xor1
        #pragma unroll
        for (int k = 0; k < 4; ++k) p[k] += dppmov<0x4E>(p[k + 4]);  // xor2
        #pragma unroll
        for (int k = 0; k < 2; ++k) p[k] += dppmov<0x141>(p[k + 2]); // xor7
        float s = p[0] + dppmov<0x128>(p[1]);                        // xor8
        s += __shfl_xor(s, 16, 64);
        s += __shfl_xor(s, 32, 64);
        if (lane < 16) red4[SA][wv * 16 + gl] = s;

        // ---- combine reduction launched at t-2 (slot SR) -> rec ----
        const float4* rp = (const float4*)(&red4[SR][0]);
        float4 f0 = f4add(f4add(rp[0], rp[4]), f4add(rp[8],  rp[12])); // s_m[0..3]
        float4 f1 = f4add(f4add(rp[1], rp[5]), f4add(rp[9],  rp[13])); // s_m[4..7]
        float4 f2 = f4add(f4add(rp[2], rp[6]), f4add(rp[10], rp[14])); // s_n[0..3]
        float4 f3 = f4add(f4add(rp[3], rp[7]), f4add(rp[11], rp[15])); // s_n[4..7]
        float prod[8] = { f0.x * f2.x, f0.y * f2.y, f0.z * f2.z, f0.w * f2.w,
                          f1.x * f3.x, f1.y * f3.y, f1.z * f3.z, f1.w * f3.w };
        float rec0 = 0.0f, rec1 = 0.0f;
        #pragma unroll
        for (int j = 0; j < 8; ++j) { rec0 += l0[j] * prod[j]; rec1 += l1[j] * prod[j]; }

        // ---- state update: x_new = 0.8*x + drive + rec_scaled ----
        const float2 dv = db[SA];
        xv.x = fmaf(0.8f, xv.x, dv.x + rec0);
        xv.y = fmaf(0.8f, xv.y, dv.y + rec1);
        xst = xv;
        *st = xst; st += 256;

        // ---- end-of-step barrier: order LDS only; vmem stays in flight ----
        asm volatile("s_waitcnt lgkmcnt(0)\n\ts_barrier" ::: "memory");
    };

    for (int t = 0; t < T_; t += 4) {
        step(t + 0, 0, xstA);
        step(t + 1, 1, xstB);
        step(t + 2, 2, xstA);
        step(t + 3, 3, xstB);
    }

    *(float2*)(xlast + (size_t)b * H_ + h0) = xv;
}

// ---------------------------------------------------------------------------
// Kernel 3: output[b,t,o] = sum_h tanh(traj[b,t,h])*W_out[o,h] + b_out[o]
// grid: (T/64, B), block 256. K=512 in 8 chunks of 64; tanh fused in staging.
// ---------------------------------------------------------------------------
__global__ __launch_bounds__(256) void out_gemm(
    const float* __restrict__ traj, const float* __restrict__ W_out,
    const float* __restrict__ b_out, float* __restrict__ out)
{
    __shared__ float4 sa4[64 * 17];  // tanh(traj) tile [64 t][16 f4]
    __shared__ float4 sb4[64 * 17];  // W_out tile [64 o][16 f4]

    const int tid = threadIdx.x;
    const int t0 = blockIdx.x * 64;
    const int b  = blockIdx.y;
    const int tg = tid >> 4, oi = tid & 15;

    float acc[4][4];
    #pragma unroll
    for (int a = 0; a < 4; ++a)
        #pragma unroll
        for (int c = 0; c < 4; ++c) acc[a][c] = 0.0f;

    const float4* tsrc = (const float4*)(traj + (size_t)(b * T_ + t0) * H_);
    const float4* wsrc = (const float4*)W_out;

    for (int hc = 0; hc < 8; ++hc) {
        const int hb4 = hc * 16;  // f4 offset within a 512-float row
        #pragma unroll
        for (int j = 0; j < 4; ++j) {
            int k = tid + 256 * j;
            int row = k >> 4, col = k & 15;
            float4 v = tsrc[(size_t)row * 128 + hb4 + col];
            v.x = ftanh(v.x); v.y = ftanh(v.y); v.z = ftanh(v.z); v.w = ftanh(v.w);
            sa4[row * 17 + col] = v;
            sb4[row * 17 + col] = wsrc[(size_t)row * 128 + hb4 + col];
        }
        __syncthreads();
        #pragma unroll
        for (int i4 = 0; i4 < 16; ++i4) {
            float4 av[4], bv[4];
            #pragma unroll
            for (int a = 0; a < 4; ++a) av[a] = sa4[(tg * 4 + a) * 17 + i4];
            #pragma unroll
            for (int c = 0; c < 4; ++c) bv[c] = sb4[(oi + 16 * c) * 17 + i4];
            #pragma unroll
            for (int a = 0; a < 4; ++a)
                #pragma unroll
                for (int c = 0; c < 4; ++c)
                    acc[a][c] += av[a].x * bv[c].x + av[a].y * bv[c].y +
                                 av[a].z * bv[c].z + av[a].w * bv[c].w;
        }
        __syncthreads();
    }

    #pragma unroll
    for (int c = 0; c < 4; ++c) {
        float bo = b_out[oi + 16 * c];
        #pragma unroll
        for (int a = 0; a < 4; ++a)
            out[(size_t)(b * T_ + t0 + tg * 4 + a) * O_ + oi + 16 * c] =
                acc[a][c] + bo;
    }
}

// ---------------------------------------------------------------------------
extern "C" void kernel_launch(void* const* d_in, const int* in_sizes, int n_in,
                              void* d_out, int out_size, void* d_ws, size_t ws_size,
                              hipStream_t stream)
{
    const float* u     = (const float*)d_in[0];
    const float* x0    = (const float*)d_in[1];
    const float* noise = (const float*)d_in[2];
    const float* L     = (const float*)d_in[3];
    const float* M     = (const float*)d_in[4];
    const float* N     = (const float*)d_in[5];
    const float* W_in  = (const float*)d_in[6];
    const float* b_in  = (const float*)d_in[7];
    const float* W_out = (const float*)d_in[8];
    const float* b_out = (const float*)d_in[9];

    float* out   = (float*)d_out;                       // [B,T,O]
    float* xlast = out + (size_t)B_ * T_ * O_;          // [B,H]
    float* traj  = xlast + (size_t)B_ * H_;             // [B,T,H]

    // 1) drive = 0.2*(u@W_in^T + b_in) + 0.05*noise -> traj region (in-place)
    inp_gemm<<<dim3(T_ / 64, H_ / 128, B_), 256, 0, stream>>>(
        u, W_in, b_in, noise, traj);
    // 2) sequential scan, one block per batch
    scan_kernel<<<dim3(B_), 256, 0, stream>>>(x0, L, M, N, traj, xlast);
    // 3) output projection
    out_gemm<<<dim3(T_ / 64, B_), 256, 0, stream>>>(traj, W_out, b_out, out);
}

// Round 2
// 675.472 us; speedup vs baseline: 1.7359x; 1.7359x over previous
//
#include <hip/hip_runtime.h>

// Problem constants (fixed by the reference setup)
#define B_ 64
#define T_ 1024
#define I_ 64
#define H_ 512
#define R_ 8
#define O_ 64

// fast tanh: tanh(x) = 1 - 2/(exp2(2*log2(e)*x)+1); well-behaved at +-inf
__device__ __forceinline__ float ftanh(float x) {
    float e = __builtin_amdgcn_exp2f(x * 2.8853900817779268f); // 2*log2(e)
    return 1.0f - 2.0f * __builtin_amdgcn_rcpf(e + 1.0f);
}

__device__ __forceinline__ float4 f4add(float4 a, float4 b) {
    return make_float4(a.x + b.x, a.y + b.y, a.z + b.z, a.w + b.w);
}

// DPP lane-permute move (VALU pipe, ~4cy; no LDS traffic)
template <int CTRL>
__device__ __forceinline__ float dppmov(float x) {
    return __int_as_float(__builtin_amdgcn_update_dpp(
        0, __float_as_int(x), CTRL, 0xF, 0xF, true));
}

// ---------------------------------------------------------------------------
// Kernel 1: drive[b,t,h] = 0.2*(sum_i u[b,t,i]*W_in[h,i] + b_in[h])
//                        + 0.05*noise[t,b,h]
// grid: (T/64, H/128, B), block 256. LDS-tiled fp32.
// ---------------------------------------------------------------------------
__global__ __launch_bounds__(256) void inp_gemm(
    const float* __restrict__ u, const float* __restrict__ W_in,
    const float* __restrict__ b_in, const float* __restrict__ noise,
    float* __restrict__ drive)
{
    __shared__ float4 su4[64 * 17];   // u tile [64 t][16 f4], row pad 17
    __shared__ float4 sw4[128 * 17];  // W tile [128 h][16 f4], row pad 17

    const int tid = threadIdx.x;
    const int t0 = blockIdx.x * 64;
    const int h0 = blockIdx.y * 128;
    const int b  = blockIdx.z;

    const float4* usrc = (const float4*)(u + (size_t)(b * T_ + t0) * I_);
    const float4* wsrc = (const float4*)(W_in + (size_t)h0 * I_);

    #pragma unroll
    for (int k = tid; k < 64 * 16; k += 256)
        su4[(k >> 4) * 17 + (k & 15)] = usrc[k];
    #pragma unroll
    for (int k = tid; k < 128 * 16; k += 256)
        sw4[(k >> 4) * 17 + (k & 15)] = wsrc[k];
    __syncthreads();

    const int tg = tid >> 4;   // 16 groups -> 4 t each
    const int hi = tid & 15;   // h = h0 + hi + 16*c

    float acc[4][8];
    #pragma unroll
    for (int a = 0; a < 4; ++a)
        #pragma unroll
        for (int c = 0; c < 8; ++c) acc[a][c] = 0.0f;

    #pragma unroll
    for (int i4 = 0; i4 < 16; ++i4) {
        float4 uv[4], wv[8];
        #pragma unroll
        for (int a = 0; a < 4; ++a) uv[a] = su4[(tg * 4 + a) * 17 + i4];
        #pragma unroll
        for (int c = 0; c < 8; ++c) wv[c] = sw4[(hi + 16 * c) * 17 + i4];
        #pragma unroll
        for (int a = 0; a < 4; ++a)
            #pragma unroll
            for (int c = 0; c < 8; ++c)
                acc[a][c] += uv[a].x * wv[c].x + uv[a].y * wv[c].y +
                             uv[a].z * wv[c].z + uv[a].w * wv[c].w;
    }

    #pragma unroll
    for (int c = 0; c < 8; ++c) {
        const int h = h0 + hi + 16 * c;
        float bi = b_in[h];
        #pragma unroll
        for (int a = 0; a < 4; ++a) {
            const int t = t0 + tg * 4 + a;
            float nz = noise[((size_t)t * B_ + b) * H_ + h];
            drive[(size_t)(b * T_ + t) * H_ + h] =
                0.2f * (acc[a][c] + bi) + 0.05f * nz;
        }
    }
}

// ---------------------------------------------------------------------------
// Kernel 2: chunk-parallel scan. The step map contracts with factor 0.8
// (rec Jacobian ~1e-6), so chunk c>=1 starts W=64 steps early from x=0 and
// warm-up converges to the true state within 0.8^64 ~ 6e-7 before emitting.
// NC chunks x B batches blocks; NC=16 -> 1024 blocks (4/CU, 16 waves/CU).
// NC=1 degenerates to the exact in-place serial scan (drive may alias traj).
//
// Per step: x_new = 0.8*x + drive[t] + rec_scaled(x_{t-2})  (rec lagged 2,
// magnitude ~4e-8). DPP fold-butterfly reduce; one raw lgkmcnt-only barrier
// per step; drive prefetch distance 3 via 4 rotating register slots.
// ---------------------------------------------------------------------------
template <int NC>
__global__ __launch_bounds__(256) void scan_chunked(
    const float* __restrict__ x0,
    const float* __restrict__ Lm, const float* __restrict__ Mm,
    const float* __restrict__ Nm,
    const float* __restrict__ drive,
    float* __restrict__ traj, float* __restrict__ xlast)
{
    constexpr int C = T_ / NC;    // emitted steps per chunk
    constexpr int W = 64;         // warm-up steps (chunks c>=1)

    const int tid  = threadIdx.x;
    const int ckid = blockIdx.x;
    const int b    = blockIdx.y;
    const int h0   = tid * 2;
    const int lane = tid & 63;
    const int wv   = tid >> 6;
    const int lm   = lane & 15;
    // linear map g: g(1)=8, g(2)=4, g(4)=14, g(8)=1  (basis match for the
    // DPP stage masks 1,2,7,8 folding value-bits 8,4,2,1)
    const int gl = ((lm & 1) ? 8 : 0) ^ ((lm & 2) ? 4 : 0) ^
                   ((lm & 4) ? 14 : 0) ^ ((lm & 8) ? 1 : 0);

    // permuted projection weights: slot k holds value v = k ^ gl
    // (v<8 -> column v of M ; v>=8 -> column v-8 of N)
    float w0[16], w1[16];
    #pragma unroll
    for (int k = 0; k < 16; ++k) {
        const int v = k ^ gl;
        const float* src = (v < 8) ? Mm : Nm;
        const int col = v & 7;
        w0[k] = src[h0 * R_ + col];
        w1[k] = src[(h0 + 1) * R_ + col];
    }
    // L columns pre-scaled by tau*scale = 0.2/(H*H)
    float l0[8], l1[8];
    const float cs = 0.2f / (512.0f * 512.0f);
    #pragma unroll
    for (int j = 0; j < 8; ++j) {
        l0[j] = Lm[h0 * R_ + j] * cs;
        l1[j] = Lm[(h0 + 1) * R_ + j] * cs;
    }

    const int emit0 = ckid * C;
    const int warm  = (ckid == 0) ? 0 : W;
    const int t0s   = emit0 - warm;       // absolute first step
    const int tend  = emit0 + C;          // absolute end

    float2 xv;
    if (ckid == 0) xv = *(const float2*)(x0 + (size_t)b * H_ + h0);
    else           xv = make_float2(0.0f, 0.0f);

    const float2* dbase = (const float2*)drive + (size_t)b * (T_ * (H_ / 2)) + tid;
    float2*       tbase = (float2*)traj  + (size_t)b * (T_ * (H_ / 2)) + tid;

    // 4 rotating reduction slots: written at k%4, read at (k+2)%4.
    __shared__ __align__(16) float red4[4][64];
    ((float*)red4)[tid] = 0.0f;   // slots read in the first 2 steps -> rec=0
    __syncthreads();

    // drive prefetch, distance 3, 4 rotating register slots
    float2 db[4];
    db[0] = dbase[(size_t)(t0s + 0) * 256];
    db[1] = dbase[(size_t)(t0s + 1) * 256];
    db[2] = dbase[(size_t)(t0s + 2) * 256];
    const float2* pf = dbase + (size_t)(t0s + 3) * 256;
    float2*       st = tbase + (size_t)emit0 * 256;
    float2 xstA, xstB;  // 2-deep store-source rotation (avoid WAR vm-waits)

#define STEP(T0, SA, XST, EMIT)                                             \
    do {                                                                    \
        const int t_ = (T0);                                                \
        constexpr int SR = ((SA) + 2) & 3;  /* combine slot (k-2) */        \
        constexpr int SP = ((SA) + 3) & 3;  /* prefetch slot (k+3) */       \
        if (t_ + 3 < tend) db[SP] = *pf;                                    \
        pf += 256;                                                          \
        /* launch reduction of entering x (consumed 2 steps later) */       \
        const float r0 = ftanh(xv.x), r1 = ftanh(xv.y);                     \
        float p[16];                                                        \
        _Pragma("unroll")                                                   \
        for (int k = 0; k < 16; ++k) p[k] = r0 * w0[k] + r1 * w1[k];        \
        _Pragma("unroll")                                                   \
        for (int k = 0; k < 8; ++k) p[k] += dppmov<0xB1>(p[k + 8]);         \
        _Pragma("unroll")                                                   \
        for (int k = 0; k < 4; ++k) p[k] += dppmov<0x4E>(p[k + 4]);         \
        _Pragma("unroll")                                                   \
        for (int k = 0; k < 2; ++k) p[k] += dppmov<0x141>(p[k + 2]);        \
        float s_ = p[0] + dppmov<0x128>(p[1]);                              \
        s_ += __shfl_xor(s_, 16, 64);                                       \
        s_ += __shfl_xor(s_, 32, 64);                                       \
        if (lane < 16) red4[SA][wv * 16 + gl] = s_;                         \
        /* combine reduction launched 2 steps ago (slot SR) -> rec */       \
        const float4* rp = (const float4*)(&red4[SR][0]);                   \
        float4 f0 = f4add(f4add(rp[0], rp[4]), f4add(rp[8],  rp[12]));      \
        float4 f1 = f4add(f4add(rp[1], rp[5]), f4add(rp[9],  rp[13]));      \
        float4 f2 = f4add(f4add(rp[2], rp[6]), f4add(rp[10], rp[14]));      \
        float4 f3 = f4add(f4add(rp[3], rp[7]), f4add(rp[11], rp[15]));      \
        float prod[8] = { f0.x * f2.x, f0.y * f2.y, f0.z * f2.z, f0.w * f2.w,\
                          f1.x * f3.x, f1.y * f3.y, f1.z * f3.z, f1.w * f3.w };\
        float rec0 = 0.0f, rec1 = 0.0f;                                     \
        _Pragma("unroll")                                                   \
        for (int j = 0; j < 8; ++j) { rec0 += l0[j] * prod[j];              \
                                      rec1 += l1[j] * prod[j]; }            \
        /* state update */                                                  \
        const float2 dv = db[SA];                                           \
        xv.x = fmaf(0.8f, xv.x, dv.x + rec0);                               \
        xv.y = fmaf(0.8f, xv.y, dv.y + rec1);                               \
        if (EMIT) { XST = xv; *st = XST; st += 256; }                       \
        /* end-of-step barrier: order LDS only; vmem stays in flight */     \
        asm volatile("s_waitcnt lgkmcnt(0)\n\ts_barrier" ::: "memory");     \
    } while (0)

    // warm-up (no store); warm is 0 or 64, both multiples of 4
    for (int k = 0; k < warm; k += 4) {
        STEP(t0s + k + 0, 0, xstA, false);
        STEP(t0s + k + 1, 1, xstB, false);
        STEP(t0s + k + 2, 2, xstA, false);
        STEP(t0s + k + 3, 3, xstB, false);
    }
    // emit
    for (int k = warm; k < warm + C; k += 4) {
        STEP(t0s + k + 0, 0, xstA, true);
        STEP(t0s + k + 1, 1, xstB, true);
        STEP(t0s + k + 2, 2, xstA, true);
        STEP(t0s + k + 3, 3, xstB, true);
    }
#undef STEP

    if (tend == T_)
        *(float2*)(xlast + (size_t)b * H_ + h0) = xv;
}

// ---------------------------------------------------------------------------
// Kernel 3: output[b,t,o] = sum_h tanh(traj[b,t,h])*W_out[o,h] + b_out[o]
// grid: (T/64, B), block 256. K=512 in 8 chunks of 64; tanh fused in staging.
// ---------------------------------------------------------------------------
__global__ __launch_bounds__(256) void out_gemm(
    const float* __restrict__ traj, const float* __restrict__ W_out,
    const float* __restrict__ b_out, float* __restrict__ out)
{
    __shared__ float4 sa4[64 * 17];  // tanh(traj) tile [64 t][16 f4]
    __shared__ float4 sb4[64 * 17];  // W_out tile [64 o][16 f4]

    const int tid = threadIdx.x;
    const int t0 = blockIdx.x * 64;
    const int b  = blockIdx.y;
    const int tg = tid >> 4, oi = tid & 15;

    float acc[4][4];
    #pragma unroll
    for (int a = 0; a < 4; ++a)
        #pragma unroll
        for (int c = 0; c < 4; ++c) acc[a][c] = 0.0f;

    const float4* tsrc = (const float4*)(traj + (size_t)(b * T_ + t0) * H_);
    const float4* wsrc = (const float4*)W_out;

    for (int hc = 0; hc < 8; ++hc) {
        const int hb4 = hc * 16;  // f4 offset within a 512-float row
        #pragma unroll
        for (int j = 0; j < 4; ++j) {
            int k = tid + 256 * j;
            int row = k >> 4, col = k & 15;
            float4 v = tsrc[(size_t)row * 128 + hb4 + col];
            v.x = ftanh(v.x); v.y = ftanh(v.y); v.z = ftanh(v.z); v.w = ftanh(v.w);
            sa4[row * 17 + col] = v;
            sb4[row * 17 + col] = wsrc[(size_t)row * 128 + hb4 + col];
        }
        __syncthreads();
        #pragma unroll
        for (int i4 = 0; i4 < 16; ++i4) {
            float4 av[4], bv[4];
            #pragma unroll
            for (int a = 0; a < 4; ++a) av[a] = sa4[(tg * 4 + a) * 17 + i4];
            #pragma unroll
            for (int c = 0; c < 4; ++c) bv[c] = sb4[(oi + 16 * c) * 17 + i4];
            #pragma unroll
            for (int a = 0; a < 4; ++a)
                #pragma unroll
                for (int c = 0; c < 4; ++c)
                    acc[a][c] += av[a].x * bv[c].x + av[a].y * bv[c].y +
                                 av[a].z * bv[c].z + av[a].w * bv[c].w;
        }
        __syncthreads();
    }

    #pragma unroll
    for (int c = 0; c < 4; ++c) {
        float bo = b_out[oi + 16 * c];
        #pragma unroll
        for (int a = 0; a < 4; ++a)
            out[(size_t)(b * T_ + t0 + tg * 4 + a) * O_ + oi + 16 * c] =
                acc[a][c] + bo;
    }
}

// ---------------------------------------------------------------------------
extern "C" void kernel_launch(void* const* d_in, const int* in_sizes, int n_in,
                              void* d_out, int out_size, void* d_ws, size_t ws_size,
                              hipStream_t stream)
{
    const float* u     = (const float*)d_in[0];
    const float* x0    = (const float*)d_in[1];
    const float* noise = (const float*)d_in[2];
    const float* L     = (const float*)d_in[3];
    const float* M     = (const float*)d_in[4];
    const float* N     = (const float*)d_in[5];
    const float* W_in  = (const float*)d_in[6];
    const float* b_in  = (const float*)d_in[7];
    const float* W_out = (const float*)d_in[8];
    const float* b_out = (const float*)d_in[9];

    float* out   = (float*)d_out;                       // [B,T,O]
    float* xlast = out + (size_t)B_ * T_ * O_;          // [B,H]
    float* traj  = xlast + (size_t)B_ * H_;             // [B,T,H]

    const size_t drive_bytes = (size_t)B_ * T_ * H_ * sizeof(float);

    if (ws_size >= drive_bytes) {
        // chunk-parallel path: drive lives in the workspace
        float* drive = (float*)d_ws;
        inp_gemm<<<dim3(T_ / 64, H_ / 128, B_), 256, 0, stream>>>(
            u, W_in, b_in, noise, drive);
        scan_chunked<16><<<dim3(16, B_), 256, 0, stream>>>(
            x0, L, M, N, drive, traj, xlast);
    } else {
        // fallback: exact serial in-place scan (drive aliases traj)
        inp_gemm<<<dim3(T_ / 64, H_ / 128, B_), 256, 0, stream>>>(
            u, W_in, b_in, noise, traj);
        scan_chunked<1><<<dim3(1, B_), 256, 0, stream>>>(
            x0, L, M, N, traj, traj, xlast);
    }

    out_gemm<<<dim3(T_ / 64, B_), 256, 0, stream>>>(traj, W_out, b_out, out);
}

// Round 3
// 567.119 us; speedup vs baseline: 2.0675x; 1.1911x over previous
//
#include <hip/hip_runtime.h>

// Problem constants (fixed by the reference setup)
#define B_ 64
#define T_ 1024
#define I_ 64
#define H_ 512
#define R_ 8
#define O_ 64

// fast tanh: tanh(x) = 1 - 2/(exp2(2*log2(e)*x)+1); well-behaved at +-inf
__device__ __forceinline__ float ftanh(float x) {
    float e = __builtin_amdgcn_exp2f(x * 2.8853900817779268f); // 2*log2(e)
    return 1.0f - 2.0f * __builtin_amdgcn_rcpf(e + 1.0f);
}

// DPP lane-permute move (VALU pipe, ~4cy; no LDS traffic)
template <int CTRL>
__device__ __forceinline__ float dppmov(float x) {
    return __int_as_float(__builtin_amdgcn_update_dpp(
        0, __float_as_int(x), CTRL, 0xF, 0xF, true));
}

// ---------------------------------------------------------------------------
// Kernel 1: drive[b,t,h] = 0.2*(sum_i u[b,t,i]*W_in[h,i] + b_in[h])
//                        + 0.05*noise[t,b,h]
// grid: (T/64, H/64, B), block 256. 64x64 tile: LDS 33.4KB -> 4 blocks/CU
// (was 52KB -> 3/CU). u tile unpadded (reads are wave-broadcast, no conflict).
// ---------------------------------------------------------------------------
__global__ __launch_bounds__(256) void inp_gemm(
    const float* __restrict__ u, const float* __restrict__ W_in,
    const float* __restrict__ b_in, const float* __restrict__ noise,
    float* __restrict__ drive)
{
    __shared__ float4 su4[64 * 16];   // u tile [64 t][16 f4], no pad (broadcast)
    __shared__ float4 sw4[64 * 17];   // W tile [64 h][16 f4], row pad 17

    const int tid = threadIdx.x;
    const int t0 = blockIdx.x * 64;
    const int h0 = blockIdx.y * 64;
    const int b  = blockIdx.z;

    const float4* usrc = (const float4*)(u + (size_t)(b * T_ + t0) * I_);
    const float4* wsrc = (const float4*)(W_in + (size_t)h0 * I_);

    #pragma unroll
    for (int k = tid; k < 64 * 16; k += 256) {
        su4[k] = usrc[k];
        sw4[(k >> 4) * 17 + (k & 15)] = wsrc[k];
    }
    __syncthreads();

    const int tg = tid >> 4;   // 16 groups -> 4 t each
    const int hi = tid & 15;   // h = h0 + hi + 16*c

    float acc[4][4];
    #pragma unroll
    for (int a = 0; a < 4; ++a)
        #pragma unroll
        for (int c = 0; c < 4; ++c) acc[a][c] = 0.0f;

    #pragma unroll
    for (int i4 = 0; i4 < 16; ++i4) {
        float4 uv[4], wv[4];
        #pragma unroll
        for (int a = 0; a < 4; ++a) uv[a] = su4[(tg * 4 + a) * 16 + i4];
        #pragma unroll
        for (int c = 0; c < 4; ++c) wv[c] = sw4[(hi + 16 * c) * 17 + i4];
        #pragma unroll
        for (int a = 0; a < 4; ++a)
            #pragma unroll
            for (int c = 0; c < 4; ++c)
                acc[a][c] += uv[a].x * wv[c].x + uv[a].y * wv[c].y +
                             uv[a].z * wv[c].z + uv[a].w * wv[c].w;
    }

    #pragma unroll
    for (int c = 0; c < 4; ++c) {
        const int h = h0 + hi + 16 * c;
        float bi = b_in[h];
        #pragma unroll
        for (int a = 0; a < 4; ++a) {
            const int t = t0 + tg * 4 + a;
            float nz = noise[((size_t)t * B_ + b) * H_ + h];
            drive[(size_t)(b * T_ + t) * H_ + h] =
                0.2f * (acc[a][c] + bi) + 0.05f * nz;
        }
    }
}

// ---------------------------------------------------------------------------
// Kernel 2: chunk-parallel scan (contraction factor 0.8 -> W=64 warm-up,
// error ~0.8^64). NC=16 -> 1024 blocks of 4 waves = 4 blocks/CU.
//
// v3 changes vs v2 (counters: VALUBusy 45%, LDS combine was 16 ds_read_b128
// + 48 adds/thread/step = ~1024 cy/CU-step of LDS occupancy alone):
//   - cross-wave combine via ds_add_f32: each wave's 16 slot-holders
//     atomically add into ONE 16-float slot; combine read collapses to
//     4 broadcast ds_read_b128, 0 adds.
//   - slot zeroing in the free rotation window (slot read at step k is
//     zeroed at k+1, re-added at k+2; all barrier-separated).
//   - combine reads issued first in the step so they hide under proj/folds.
// ---------------------------------------------------------------------------
template <int NC>
__global__ __launch_bounds__(256) void scan_chunked(
    const float* __restrict__ x0,
    const float* __restrict__ Lm, const float* __restrict__ Mm,
    const float* __restrict__ Nm,
    const float* __restrict__ drive,
    float* __restrict__ traj, float* __restrict__ xlast)
{
    constexpr int C = T_ / NC;    // emitted steps per chunk
    constexpr int W = 64;         // warm-up steps (chunks c>=1)

    const int tid  = threadIdx.x;
    const int ckid = blockIdx.x;
    const int b    = blockIdx.y;
    const int h0   = tid * 2;
    const int lane = tid & 63;
    const int lm   = lane & 15;
    // linear map g: g(1)=8, g(2)=4, g(4)=14, g(8)=1  (basis match for the
    // DPP stage masks 1,2,7,8 folding value-bits 8,4,2,1)
    const int gl = ((lm & 1) ? 8 : 0) ^ ((lm & 2) ? 4 : 0) ^
                   ((lm & 4) ? 14 : 0) ^ ((lm & 8) ? 1 : 0);

    // permuted projection weights: slot k holds value v = k ^ gl
    // (v<8 -> column v of M ; v>=8 -> column v-8 of N)
    float w0[16], w1[16];
    #pragma unroll
    for (int k = 0; k < 16; ++k) {
        const int v = k ^ gl;
        const float* src = (v < 8) ? Mm : Nm;
        const int col = v & 7;
        w0[k] = src[h0 * R_ + col];
        w1[k] = src[(h0 + 1) * R_ + col];
    }
    // L columns pre-scaled by tau*scale = 0.2/(H*H)
    float l0[8], l1[8];
    const float cs = 0.2f / (512.0f * 512.0f);
    #pragma unroll
    for (int j = 0; j < 8; ++j) {
        l0[j] = Lm[h0 * R_ + j] * cs;
        l1[j] = Lm[(h0 + 1) * R_ + j] * cs;
    }

    const int emit0 = ckid * C;
    const int warm  = (ckid == 0) ? 0 : W;
    const int t0s   = emit0 - warm;       // absolute first step
    const int tend  = emit0 + C;          // absolute end

    float2 xv;
    if (ckid == 0) xv = *(const float2*)(x0 + (size_t)b * H_ + h0);
    else           xv = make_float2(0.0f, 0.0f);

    const float2* dbase = (const float2*)drive + (size_t)b * (T_ * (H_ / 2)) + tid;
    float2*       tbase = (float2*)traj  + (size_t)b * (T_ * (H_ / 2)) + tid;

    // 4 rotating 16-float accumulation slots:
    //   slot s: ds_add at steps k==s (mod4), read at k==s+2, zeroed at k==s+3
    __shared__ __align__(16) float red[4][16];
    if (tid < 64) ((float*)red)[tid] = 0.0f;
    __syncthreads();

    // drive prefetch, distance 3, 4 rotating register slots
    float2 db[4];
    db[0] = dbase[(size_t)(t0s + 0) * 256];
    db[1] = dbase[(size_t)(t0s + 1) * 256];
    db[2] = dbase[(size_t)(t0s + 2) * 256];
    const float2* pf = dbase + (size_t)(t0s + 3) * 256;
    float2*       st = tbase + (size_t)emit0 * 256;
    float2 xstA, xstB;  // 2-deep store-source rotation (avoid WAR vm-waits)

#define STEP(T0, SA, XST, EMIT)                                             \
    do {                                                                    \
        const int t_ = (T0);                                                \
        constexpr int SR = ((SA) + 2) & 3;  /* combine slot (added k-2) */  \
        constexpr int SZ = ((SA) + 1) & 3;  /* zero slot (read at k-1) */   \
        constexpr int SP = ((SA) + 3) & 3;  /* prefetch slot (used k+3) */  \
        /* issue combine reads early: hidden under proj/folds */            \
        const float4* rp = (const float4*)(&red[SR][0]);                    \
        const float4 f0 = rp[0], f1 = rp[1], f2 = rp[2], f3 = rp[3];        \
        if (t_ + 3 < tend) db[SP] = *pf;                                    \
        pf += 256;                                                          \
        /* launch reduction of entering x (consumed 2 steps later) */       \
        const float r0 = ftanh(xv.x), r1 = ftanh(xv.y);                     \
        float p[16];                                                        \
        _Pragma("unroll")                                                   \
        for (int k = 0; k < 16; ++k) p[k] = r0 * w0[k] + r1 * w1[k];        \
        _Pragma("unroll")                                                   \
        for (int k = 0; k < 8; ++k) p[k] += dppmov<0xB1>(p[k + 8]);         \
        _Pragma("unroll")                                                   \
        for (int k = 0; k < 4; ++k) p[k] += dppmov<0x4E>(p[k + 4]);         \
        _Pragma("unroll")                                                   \
        for (int k = 0; k < 2; ++k) p[k] += dppmov<0x141>(p[k + 2]);        \
        float s_ = p[0] + dppmov<0x128>(p[1]);                              \
        s_ += __shfl_xor(s_, 16, 64);                                       \
        s_ += __shfl_xor(s_, 32, 64);                                       \
        if (lane < 16) {                                                    \
            red[SZ][lane] = 0.0f;           /* re-zero slot read at k-1 */  \
            atomicAdd(&red[SA][gl], s_);    /* ds_add_f32, no return */     \
        }                                                                   \
        /* combine (pure reads): prod & rec from slot SR */                 \
        float prod[8] = { f0.x * f2.x, f0.y * f2.y, f0.z * f2.z, f0.w * f2.w,\
                          f1.x * f3.x, f1.y * f3.y, f1.z * f3.z, f1.w * f3.w };\
        float rec0 = 0.0f, rec1 = 0.0f;                                     \
        _Pragma("unroll")                                                   \
        for (int j = 0; j < 8; ++j) { rec0 += l0[j] * prod[j];              \
                                      rec1 += l1[j] * prod[j]; }            \
        /* state update */                                                  \
        const float2 dv = db[SA];                                           \
        xv.x = fmaf(0.8f, xv.x, dv.x + rec0);                               \
        xv.y = fmaf(0.8f, xv.y, dv.y + rec1);                               \
        if (EMIT) { XST = xv; *st = XST; st += 256; }                       \
        /* end-of-step barrier: order LDS only; vmem stays in flight */     \
        asm volatile("s_waitcnt lgkmcnt(0)\n\ts_barrier" ::: "memory");     \
    } while (0)

    // warm-up (no store); warm is 0 or 64, both multiples of 4
    for (int k = 0; k < warm; k += 4) {
        STEP(t0s + k + 0, 0, xstA, false);
        STEP(t0s + k + 1, 1, xstB, false);
        STEP(t0s + k + 2, 2, xstA, false);
        STEP(t0s + k + 3, 3, xstB, false);
    }
    // emit
    for (int k = warm; k < warm + C; k += 4) {
        STEP(t0s + k + 0, 0, xstA, true);
        STEP(t0s + k + 1, 1, xstB, true);
        STEP(t0s + k + 2, 2, xstA, true);
        STEP(t0s + k + 3, 3, xstB, true);
    }
#undef STEP

    if (tend == T_)
        *(float2*)(xlast + (size_t)b * H_ + h0) = xv;
}

// ---------------------------------------------------------------------------
// Kernel 3: output[b,t,o] = sum_h tanh(traj[b,t,h])*W_out[o,h] + b_out[o]
// grid: (T/64, B), block 256. K=512 in 8 chunks of 64; tanh fused in staging.
// ---------------------------------------------------------------------------
__global__ __launch_bounds__(256) void out_gemm(
    const float* __restrict__ traj, const float* __restrict__ W_out,
    const float* __restrict__ b_out, float* __restrict__ out)
{
    __shared__ float4 sa4[64 * 17];  // tanh(traj) tile [64 t][16 f4]
    __shared__ float4 sb4[64 * 17];  // W_out tile [64 o][16 f4]

    const int tid = threadIdx.x;
    const int t0 = blockIdx.x * 64;
    const int b  = blockIdx.y;
    const int tg = tid >> 4, oi = tid & 15;

    float acc[4][4];
    #pragma unroll
    for (int a = 0; a < 4; ++a)
        #pragma unroll
        for (int c = 0; c < 4; ++c) acc[a][c] = 0.0f;

    const float4* tsrc = (const float4*)(traj + (size_t)(b * T_ + t0) * H_);
    const float4* wsrc = (const float4*)W_out;

    for (int hc = 0; hc < 8; ++hc) {
        const int hb4 = hc * 16;  // f4 offset within a 512-float row
        #pragma unroll
        for (int j = 0; j < 4; ++j) {
            int k = tid + 256 * j;
            int row = k >> 4, col = k & 15;
            float4 v = tsrc[(size_t)row * 128 + hb4 + col];
            v.x = ftanh(v.x); v.y = ftanh(v.y); v.z = ftanh(v.z); v.w = ftanh(v.w);
            sa4[row * 17 + col] = v;
            sb4[row * 17 + col] = wsrc[(size_t)row * 128 + hb4 + col];
        }
        __syncthreads();
        #pragma unroll
        for (int i4 = 0; i4 < 16; ++i4) {
            float4 av[4], bv[4];
            #pragma unroll
            for (int a = 0; a < 4; ++a) av[a] = sa4[(tg * 4 + a) * 17 + i4];
            #pragma unroll
            for (int c = 0; c < 4; ++c) bv[c] = sb4[(oi + 16 * c) * 17 + i4];
            #pragma unroll
            for (int a = 0; a < 4; ++a)
                #pragma unroll
                for (int c = 0; c < 4; ++c)
                    acc[a][c] += av[a].x * bv[c].x + av[a].y * bv[c].y +
                                 av[a].z * bv[c].z + av[a].w * bv[c].w;
        }
        __syncthreads();
    }

    #pragma unroll
    for (int c = 0; c < 4; ++c) {
        float bo = b_out[oi + 16 * c];
        #pragma unroll
        for (int a = 0; a < 4; ++a)
            out[(size_t)(b * T_ + t0 + tg * 4 + a) * O_ + oi + 16 * c] =
                acc[a][c] + bo;
    }
}

// ---------------------------------------------------------------------------
extern "C" void kernel_launch(void* const* d_in, const int* in_sizes, int n_in,
                              void* d_out, int out_size, void* d_ws, size_t ws_size,
                              hipStream_t stream)
{
    const float* u     = (const float*)d_in[0];
    const float* x0    = (const float*)d_in[1];
    const float* noise = (const float*)d_in[2];
    const float* L     = (const float*)d_in[3];
    const float* M     = (const float*)d_in[4];
    const float* N     = (const float*)d_in[5];
    const float* W_in  = (const float*)d_in[6];
    const float* b_in  = (const float*)d_in[7];
    const float* W_out = (const float*)d_in[8];
    const float* b_out = (const float*)d_in[9];

    float* out   = (float*)d_out;                       // [B,T,O]
    float* xlast = out + (size_t)B_ * T_ * O_;          // [B,H]
    float* traj  = xlast + (size_t)B_ * H_;             // [B,T,H]

    const size_t drive_bytes = (size_t)B_ * T_ * H_ * sizeof(float);

    if (ws_size >= drive_bytes) {
        // chunk-parallel path: drive lives in the workspace
        float* drive = (float*)d_ws;
        inp_gemm<<<dim3(T_ / 64, H_ / 64, B_), 256, 0, stream>>>(
            u, W_in, b_in, noise, drive);
        scan_chunked<16><<<dim3(16, B_), 256, 0, stream>>>(
            x0, L, M, N, drive, traj, xlast);
    } else {
        // fallback: exact serial in-place scan (drive aliases traj)
        inp_gemm<<<dim3(T_ / 64, H_ / 64, B_), 256, 0, stream>>>(
            u, W_in, b_in, noise, traj);
        scan_chunked<1><<<dim3(1, B_), 256, 0, stream>>>(
            x0, L, M, N, traj, traj, xlast);
    }

    out_gemm<<<dim3(T_ / 64, B_), 256, 0, stream>>>(traj, W_out, b_out, out);
}